// Round 4
// baseline (27.373 us; speedup 1.0000x reference)
//
#include <hip/hip_runtime.h>

// Bspline control-grid -> dense flow field
// inputs: [B=16, T=25, 2*32*32] fp32  -> [N=400, 32, 32, 2] control grids
// output: [16, 25, 192, 192, 2] fp32 = -192 * bilinear_upsample(grid)
//
// Separable: per block (16 output rows of one image), cooperatively compute
// y-lerped rows py[16][32][2] into LDS (pre-scaled by -192); hot loop is
// x-lerp only (2 LDS float2 reads + 4 flops per pixel, 32 B stores/iter).
//
// XCD swizzle: physical blockIdx -> (n = bid % 400, chunk = bid / 400).
// Hardware round-robins blocks across 8 XCDs; 400 % 8 == 0 so all 12 blocks
// of image n land on XCD n%8 -> each 8 KB grid fetched into exactly ONE L2
// (input HBM traffic 26 MB -> 3.3 MB).

#define GDIM 32
#define HOUT 192
#define WOUT 192
#define NIMG 400
#define ROWS_PER_BLOCK 16
#define BLOCKS_PER_IMG (HOUT / ROWS_PER_BLOCK)   // 12
#define THREADS 256
#define QUADS_PER_ROW (WOUT / 4)                 // 48

typedef float f4 __attribute__((ext_vector_type(4)));

__global__ __launch_bounds__(THREADS) void bspline_flow_kernel(
    const float* __restrict__ in, float* __restrict__ out) {
  __shared__ float2 py[ROWS_PER_BLOCK][GDIM];   // y-lerped rows * -192 (4 KB)

  const int bid   = blockIdx.x;
  const int n     = bid % NIMG;                 // image: same XCD for all its blocks
  const int chunk = bid / NIMG;                 // 0..11
  const int tid   = threadIdx.x;
  const int row0  = chunk * ROWS_PER_BLOCK;

  const float qscale = 31.0f / 192.0f;

  // Stage: y-interpolate the control grid for this block's 16 rows.
  // 16 rows x 32 cols = 512 float2 -> 2 per thread; -192 folded into weights.
  {
    const float2* g = reinterpret_cast<const float2*>(in) + (size_t)n * (GDIM * GDIM);
#pragma unroll
    for (int s = 0; s < 2; ++s) {
      const int j  = tid + s * THREADS;      // 0..511
      const int r  = j >> 5;                 // local row 0..15
      const int c  = j & 31;                 // grid col 0..31
      const int y  = row0 + r;
      const float qy = (float)y * qscale;
      const float fy = floorf(qy);
      const int   y0 = (int)fy;              // <= 30 always
      const float ay = (qy - fy) * -192.0f;
      const float by = -192.0f - ay;         // (1-a) * -192
      const float2 gA = g[y0 * GDIM + c];
      const float2 gB = g[(y0 + 1) * GDIM + c];
      float2 v;
      v.x = gA.x * by + gB.x * ay;
      v.y = gA.y * by + gB.y * ay;
      py[r][c] = v;
    }
  }
  __syncthreads();

  f4* outv = reinterpret_cast<f4*>(out + (size_t)n * (HOUT * WOUT * 2));

  // Hot loop: 3 iterations, each = 4 pixels (one quad), 2 float4 stores.
#pragma unroll
  for (int it = 0; it < 3; ++it) {
    const int t  = tid + it * THREADS;       // 0..767
    const int yl = t / QUADS_PER_ROW;        // 0..15 (magic-mul)
    const int q  = t - yl * QUADS_PER_ROW;   // quad index 0..47
    const int y  = row0 + yl;
    const float2* prow = py[yl];

    float res[8];
#pragma unroll
    for (int k = 0; k < 4; ++k) {
      const int   x  = 4 * q + k;
      const float qx = (float)x * qscale;
      const float fx = floorf(qx);
      const int   x0 = (int)fx;              // <= 30 always
      const float ax = qx - fx, bx = 1.0f - ax;
      const float2 p0 = prow[x0];
      const float2 p1 = prow[x0 + 1];
      res[2 * k + 0] = p0.x * bx + p1.x * ax;
      res[2 * k + 1] = p0.y * bx + p1.y * ax;
    }

    f4 o0 = {res[0], res[1], res[2], res[3]};
    f4 o1 = {res[4], res[5], res[6], res[7]};
    const size_t base = (size_t)y * (WOUT / 2) + 2 * q;
    outv[base]     = o0;
    outv[base + 1] = o1;
  }
}

extern "C" void kernel_launch(void* const* d_in, const int* in_sizes, int n_in,
                              void* d_out, int out_size, void* d_ws, size_t ws_size,
                              hipStream_t stream) {
  const float* in = (const float*)d_in[0];
  float* out = (float*)d_out;
  dim3 grid(NIMG * BLOCKS_PER_IMG);
  bspline_flow_kernel<<<grid, THREADS, 0, stream>>>(in, out);
}